// Round 2
// baseline (428.926 us; speedup 1.0000x reference)
//
#include <hip/hip_runtime.h>
#include <hip/hip_bf16.h>

#define D 128
#define K 32
#define NB 20000
#define NPB 4                 // nodes per block (one wave per node)
#define NBLK (NB / NPB)       // 5000 blocks
#define NROWS 33
#define FSTR 64               // fbuf row stride in dwords (128 bf16)

typedef unsigned short u16;
typedef unsigned int   u32;

__device__ inline float blo(u32 v) { return __uint_as_float(v << 16); }
__device__ inline float bhi(u32 v) { return __uint_as_float(v & 0xffff0000u); }
__device__ inline u32 f2b_rne(float x) {           // fp32 -> bf16 (round-nearest-even)
    u32 u = __float_as_uint(x);
    return (u + 0x7fffu + ((u >> 16) & 1u)) >> 16;
}
__device__ inline u32 pack2(float a, float b) { return f2b_rne(a) | (f2b_rne(b) << 16); }

// ---------------------------------------------------------------------------
// Precompute: w12[0..127] = kernel1 @ aw[0:128]   (score vec for neighbours)
//             w12[128..255] = kernel @ aw[128:256] (score vec for node)
//             MTb[u][d] = sum_e kernel1[d][e]*nw[e][u], stored bf16
// ---------------------------------------------------------------------------
__global__ __launch_bounds__(256)
void precompute_kernel(const float* __restrict__ k0, const float* __restrict__ k1,
                       const float* __restrict__ aw, const float* __restrict__ nw,
                       float* __restrict__ w12, u16* __restrict__ MTb)
{
    int t = threadIdx.x;
    if (blockIdx.x < 64) {
        int gid = blockIdx.x * 256 + t;
        int u = gid & 127, d = gid >> 7;
        float acc = 0.f;
        #pragma unroll 8
        for (int e = 0; e < D; ++e)
            acc = fmaf(k1[d * D + e], nw[e * D + u], acc);
        MTb[u * D + d] = (u16)f2b_rne(acc);
    } else {
        if (t < 128) {
            float acc = 0.f;
            #pragma unroll 8
            for (int e = 0; e < D; ++e)
                acc = fmaf(k1[t * D + e], aw[e], acc);
            w12[t] = acc;
        } else {
            int d = t - 128;
            float acc = 0.f;
            #pragma unroll 8
            for (int e = 0; e < D; ++e)
                acc = fmaf(k0[d * D + e], aw[128 + e], acc);
            w12[t] = acc;
        }
    }
}

// ---------------------------------------------------------------------------
// Main kernel: 4 nodes per 256-thread block, ONE WAVE PER NODE, ZERO BARRIERS.
// Wave n owns node n: its 32 neighbour rows (fbuf rows 4k+n), its target row,
// its softmax, its aggregate, its epilogue.  All LDS traffic is wave-private
// (wave-internal DS ordering suffices; no __syncthreads anywhere).
//   - half-wave h of wave n handles neighbour rows k = 2i+h (i=0..15);
//     half 0 additionally handles the target row.
//   - scores never touch LDS: select-accumulate per row into `sc`, then one
//     __shfl redistributes so lane cc holds score[k=cc].
//   - aggregate stays in registers (lane l holds d=2l,2l+1) and feeds the
//     epilogue via __shfl broadcasts; lane l produces out[u=l] and out[u=l+64].
// ---------------------------------------------------------------------------
__global__ __launch_bounds__(256, 4)
void gat4_kernel(const float* __restrict__ features,
                 const int* __restrict__ node,
                 const int* __restrict__ neigh,
                 const float* __restrict__ w12g,   // [256]
                 const u16* __restrict__ MTb,      // [D][D] bf16, MTb[u][d]
                 float* __restrict__ out)          // [NB][D] fp32
{
    __shared__ u32 fbuf[128 * FSTR];       // exactly 32 KB, wave-partitioned

    const int t  = threadIdx.x;
    const int b4 = blockIdx.x * NPB;
    const int n  = t >> 6;                 // wave index == node index
    const int l  = t & 63;                 // lane in wave
    const int cc = l & 31;                 // lane in half-wave (float4 column)
    const int h  = l >> 5;                 // half-wave

    // score weight vectors (tiny, L2-hot, coalesced)
    const float4* w4 = (const float4*)w12g;
    const float4 wlo = w4[cc];             // neighbour-row weights
    const float4 whi = w4[32 + cc];        // target-row weights

    // one coalesced index load: lane cc holds neighbour k=cc (dup across halves)
    const int idxv = neigh[(b4 + n) * K + cc];
    const int tidx = node[b4 + n];

    const float4* f4 = (const float4*)features;

    // ---- stage 1: issue first 8 rows + target (peak ~10 rows live) ----
    float4 v0[8], v1[8], vt;
    #pragma unroll
    for (int i = 0; i < 8; ++i)
        v0[i] = f4[(size_t)__shfl(idxv, 2 * i + h) * 32 + cc];
    if (h == 0) vt = f4[(size_t)tidx * 32 + cc];

    float sc = 0.f, sct = 0.f;

    // ---- stage 2: issue row i+8 while consuming row i (pack + fused score) ----
    #pragma unroll
    for (int i = 0; i < 8; ++i) {
        v1[i] = f4[(size_t)__shfl(idxv, 2 * (i + 8) + h) * 32 + cc];
        const int r = 4 * (2 * i + h) + n;           // fbuf row for k=2i+h
        u32* dst = &fbuf[r * FSTR + cc * 2];
        dst[0] = pack2(v0[i].x, v0[i].y);
        dst[1] = pack2(v0[i].z, v0[i].w);
        float p = v0[i].x * wlo.x + v0[i].y * wlo.y + v0[i].z * wlo.z + v0[i].w * wlo.w;
        p += __shfl_xor(p, 1);
        p += __shfl_xor(p, 2);
        p += __shfl_xor(p, 4);
        p += __shfl_xor(p, 8);
        p += __shfl_xor(p, 16);
        if ((cc >> 1) == i) sc = p;                  // lane cc keeps k=(cc&~1)|h
    }

    // ---- target-row score (half 0 only; all its lanes end up holding it) ----
    if (h == 0) {
        float p = vt.x * whi.x + vt.y * whi.y + vt.z * whi.z + vt.w * whi.w;
        p += __shfl_xor(p, 1);
        p += __shfl_xor(p, 2);
        p += __shfl_xor(p, 4);
        p += __shfl_xor(p, 8);
        p += __shfl_xor(p, 16);
        sct = p;
    }

    // ---- stage 3: consume rows 8..15 ----
    #pragma unroll
    for (int i = 0; i < 8; ++i) {
        const int k = 2 * (i + 8) + h;
        const int r = 4 * k + n;
        u32* dst = &fbuf[r * FSTR + cc * 2];
        dst[0] = pack2(v1[i].x, v1[i].y);
        dst[1] = pack2(v1[i].z, v1[i].w);
        float p = v1[i].x * wlo.x + v1[i].y * wlo.y + v1[i].z * wlo.z + v1[i].w * wlo.w;
        p += __shfl_xor(p, 1);
        p += __shfl_xor(p, 2);
        p += __shfl_xor(p, 4);
        p += __shfl_xor(p, 8);
        p += __shfl_xor(p, 16);
        if ((cc >> 1) == i + 8) sc = p;
    }

    // ---- softmax, fully in registers ----
    // lane l=32h+cc holds sc = score[(cc&~1)|h]; lane wanting k=cc reads
    // half (cc&1), lane cc (whose own k is exactly cc).
    float vsc = __shfl(sc, ((cc & 1) << 5) | cc);
    vsc += __shfl(sct, 0);                           // + target score
    vsc = vsc > 0.f ? vsc : 0.2f * vsc;              // leaky relu
    float m = vsc;
    m = fmaxf(m, __shfl_xor(m, 1));
    m = fmaxf(m, __shfl_xor(m, 2));
    m = fmaxf(m, __shfl_xor(m, 4));
    m = fmaxf(m, __shfl_xor(m, 8));
    m = fmaxf(m, __shfl_xor(m, 16));
    float e = __expf(vsc - m);
    float s = e;
    s += __shfl_xor(s, 1);
    s += __shfl_xor(s, 2);
    s += __shfl_xor(s, 4);
    s += __shfl_xor(s, 8);
    s += __shfl_xor(s, 16);
    const float a = e * (1.0f / s);                  // lane l holds alpha[k=cc]

    // ---- aggregate from this wave's own fbuf rows (no barrier needed) ----
    float a0 = 0.f, a1 = 0.f;                        // lane l accumulates d=2l, 2l+1
    #pragma unroll
    for (int k = 0; k < K; ++k) {
        float al = __shfl(a, k);                     // readlane broadcast
        u32 vv = fbuf[(4 * k + n) * FSTR + l];
        a0 = fmaf(al, blo(vv), a0);
        a1 = fmaf(al, bhi(vv), a1);
    }

    // ---- epilogue: out[n][u] = sum_d agg[d]*MT[u][d]; lane l does u=l, l+64 ----
    const uint4* mrowA = (const uint4*)(MTb + (size_t)l * D);
    const uint4* mrowB = (const uint4*)(MTb + (size_t)(l + 64) * D);
    float accA = 0.f, accB = 0.f;
    #pragma unroll
    for (int q = 0; q < 16; ++q) {
        float g0 = __shfl(a0, 4 * q + 0), g1 = __shfl(a1, 4 * q + 0);
        float g2 = __shfl(a0, 4 * q + 1), g3 = __shfl(a1, 4 * q + 1);
        float g4 = __shfl(a0, 4 * q + 2), g5 = __shfl(a1, 4 * q + 2);
        float g6 = __shfl(a0, 4 * q + 3), g7 = __shfl(a1, 4 * q + 3);
        uint4 x = mrowA[q], y = mrowB[q];
        accA += g0 * blo(x.x) + g1 * bhi(x.x) + g2 * blo(x.y) + g3 * bhi(x.y)
              + g4 * blo(x.z) + g5 * bhi(x.z) + g6 * blo(x.w) + g7 * bhi(x.w);
        accB += g0 * blo(y.x) + g1 * bhi(y.x) + g2 * blo(y.y) + g3 * bhi(y.y)
              + g4 * blo(y.z) + g5 * bhi(y.z) + g6 * blo(y.w) + g7 * bhi(y.w);
    }
    out[(size_t)(b4 + n) * D + l]      = accA;
    out[(size_t)(b4 + n) * D + 64 + l] = accB;
}

// ---------------------------------------------------------------------------
// Fallback (ws too small): round-4 known-good fp32 path, scratch-free.
// ---------------------------------------------------------------------------
#define RS 33
#define RSF 132
__global__ __launch_bounds__(256)
void gat_fallback_kernel(const float* __restrict__ features, const int* __restrict__ node,
                         const int* __restrict__ neigh,
                         const float* __restrict__ k0, const float* __restrict__ k1,
                         const float* __restrict__ aw, const float* __restrict__ nw,
                         float* __restrict__ out)
{
    __shared__ float4 fbuf[NROWS * RS];
    __shared__ float w1[D], w2[D], h[D];
    __shared__ int   idxs[NROWS];
    __shared__ float psum[NROWS][8];
    __shared__ float zb[NROWS], alpha[K], agg[D];

    const int b = blockIdx.x, t = threadIdx.x;

    if (t < 128) {
        float a = 0.f;
        for (int e = 0; e < D; ++e) a = fmaf(k1[t * D + e], aw[e], a);
        w1[t] = a;
    } else {
        int d = t - 128;
        float a = 0.f;
        for (int e = 0; e < D; ++e) a = fmaf(k0[d * D + e], aw[128 + e], a);
        w2[d] = a;
    }
    if (t < K)       idxs[t] = neigh[b * K + t];
    else if (t == K) idxs[K] = node[b];
    __syncthreads();

    const float4* f4 = (const float4*)features;
    for (int c = t; c < NROWS * 32; c += 256) {
        int j = c >> 5, cc = c & 31;
        fbuf[j * RS + cc] = f4[(size_t)idxs[j] * 32 + cc];
    }
    __syncthreads();

    for (int task = t; task < NROWS * 8; task += 256) {
        int j = task >> 3, sub = task & 7;
        const float* w = (j < K) ? w1 : w2;
        const float4* r = &fbuf[j * RS + sub * 4];
        int d0 = sub * 16;
        float4 a0 = r[0], a1 = r[1], a2 = r[2], a3 = r[3];
        float acc;
        acc  = a0.x * w[d0 + 0]  + a0.y * w[d0 + 1]  + a0.z * w[d0 + 2]  + a0.w * w[d0 + 3];
        acc += a1.x * w[d0 + 4]  + a1.y * w[d0 + 5]  + a1.z * w[d0 + 6]  + a1.w * w[d0 + 7];
        acc += a2.x * w[d0 + 8]  + a2.y * w[d0 + 9]  + a2.z * w[d0 + 10] + a2.w * w[d0 + 11];
        acc += a3.x * w[d0 + 12] + a3.y * w[d0 + 13] + a3.z * w[d0 + 14] + a3.w * w[d0 + 15];
        psum[j][sub] = acc;
    }
    __syncthreads();

    if (t < NROWS) {
        float s = 0.f;
        #pragma unroll
        for (int i = 0; i < 8; ++i) s += psum[t][i];
        zb[t] = s;
    }
    __syncthreads();

    if (t == 0) {
        float c = zb[K];
        float m = -1e30f;
        #pragma unroll
        for (int k = 0; k < K; ++k) {
            float v = zb[k] + c;
            v = v > 0.f ? v : 0.2f * v;
            zb[k] = v;
            m = fmaxf(m, v);
        }
        float s = 0.f;
        #pragma unroll
        for (int k = 0; k < K; ++k) { float e = __expf(zb[k] - m); alpha[k] = e; s += e; }
        float inv = 1.f / s;
        #pragma unroll
        for (int k = 0; k < K; ++k) alpha[k] *= inv;
    }
    __syncthreads();

    const float* fb = (const float*)fbuf;
    if (t < D) {
        float a = 0.f;
        #pragma unroll
        for (int k = 0; k < K; ++k)
            a = fmaf(alpha[k], fb[k * RSF + t], a);
        agg[t] = a;
    }
    __syncthreads();

    if (t < 128) {
        float acc = 0.f;
        for (int d = 0; d < D; ++d) acc = fmaf(agg[d], k1[d * D + t], acc);
        h[t] = acc;
    }
    __syncthreads();
    if (t < 128) {
        float acc = 0.f;
        for (int e = 0; e < D; ++e) acc = fmaf(h[e], nw[e * D + t], acc);
        out[(size_t)b * D + t] = acc;
    }
}

extern "C" void kernel_launch(void* const* d_in, const int* in_sizes, int n_in,
                              void* d_out, int out_size, void* d_ws, size_t ws_size,
                              hipStream_t stream) {
    const float* features = (const float*)d_in[0];
    const int*   node     = (const int*)d_in[1];
    const int*   neigh    = (const int*)d_in[2];
    const float* k0       = (const float*)d_in[3];
    const float* k1       = (const float*)d_in[4];
    const float* aw       = (const float*)d_in[5];
    const float* nw       = (const float*)d_in[6];

    // ws layout: w12 (256 f32, 1 KB) | MTb (128*128 bf16, 32 KB)
    const size_t need = 256 * sizeof(float) + (size_t)D * D * sizeof(u16);
    if (ws_size >= need) {
        float* w12 = (float*)d_ws;
        u16*   MTb = (u16*)(w12 + 256);
        precompute_kernel<<<65, 256, 0, stream>>>(k0, k1, aw, nw, w12, MTb);
        gat4_kernel<<<NBLK, 256, 0, stream>>>(features, node, neigh, w12, MTb,
                                              (float*)d_out);
    } else {
        gat_fallback_kernel<<<NB, 256, 0, stream>>>(features, node, neigh,
                                                    k0, k1, aw, nw, (float*)d_out);
    }
}

// Round 3
// 384.008 us; speedup vs baseline: 1.1170x; 1.1170x over previous
//
#include <hip/hip_runtime.h>
#include <hip/hip_bf16.h>

#define D 128
#define K 32
#define NB 20000
#define NPB 4                 // nodes per block
#define NBLK (NB / NPB)       // 5000 blocks
#define NROWS 33              // per node: 32 neighbours + 1 target
#define FSTR 64               // fbuf row stride in dwords (128 bf16, contiguous rows)

typedef unsigned short u16;
typedef unsigned int   u32;

__device__ inline float blo(u32 v) { return __uint_as_float(v << 16); }
__device__ inline float bhi(u32 v) { return __uint_as_float(v & 0xffff0000u); }
__device__ inline u32 f2b_rne(float x) {           // fp32 -> bf16 (round-nearest-even)
    u32 u = __float_as_uint(x);
    return (u + 0x7fffu + ((u >> 16) & 1u)) >> 16;
}
// pair-convert via compiler (emits v_cvt_pk_bf16_f32 on gfx950); RNE like f2b_rne
__device__ inline u32 packcvt(float a, float b) {
    __hip_bfloat162 h = __float22bfloat162_rn(make_float2(a, b));
    union { __hip_bfloat162 h2; u32 u; } cv;
    cv.h2 = h;
    return cv.u;                                   // a in low 16, b in high 16
}

// ---------------------------------------------------------------------------
// Precompute: w12[0..127] = kernel1 @ aw[0:128]   (score vec for neighbours)
//             w12[128..255] = kernel @ aw[128:256] (score vec for node)
//             MTb[u][d] = sum_e kernel1[d][e]*nw[e][u], stored bf16
// blocks 0..63 -> MTb (u thread-fast: nw coalesced, k1 broadcast); block 64 -> w12.
// ---------------------------------------------------------------------------
__global__ __launch_bounds__(256)
void precompute_kernel(const float* __restrict__ k0, const float* __restrict__ k1,
                       const float* __restrict__ aw, const float* __restrict__ nw,
                       float* __restrict__ w12, u16* __restrict__ MTb)
{
    int t = threadIdx.x;
    if (blockIdx.x < 64) {
        int gid = blockIdx.x * 256 + t;
        int u = gid & 127, d = gid >> 7;
        float acc = 0.f;
        #pragma unroll 8
        for (int e = 0; e < D; ++e)
            acc = fmaf(k1[d * D + e], nw[e * D + u], acc);
        MTb[u * D + d] = (u16)f2b_rne(acc);
    } else {
        if (t < 128) {
            float acc = 0.f;
            #pragma unroll 8
            for (int e = 0; e < D; ++e)
                acc = fmaf(k1[t * D + e], aw[e], acc);
            w12[t] = acc;
        } else {
            int d = t - 128;
            float acc = 0.f;
            #pragma unroll 8
            for (int e = 0; e < D; ++e)
                acc = fmaf(k0[d * D + e], aw[128 + e], acc);
            w12[t] = acc;
        }
    }
}

// ---------------------------------------------------------------------------
// Main kernel: 4 nodes per 256-thread block.  3 phases, 2 barriers.
// (Round-1 structure — proven fastest.  The 17-deep register-held load batch
//  in P1 is THE critical property: no min-waves launch bound, so the
//  register allocator keeps all rows in flight.)
//   P1 : batched gather (fp32 global -> bf16 LDS) with fused score
//        (shfl-reduced, fp32 exact).  Target rows are scored but not stored;
//        only waves 0-1 load them (waves 2-3 skip the duplicate load).
//   P2': per-wave softmax fully in registers (tree shfl reduce, all 4 waves
//        active) fused with the bf16 aggregate.
//   P4 : epilogue out = agg @ MT (bf16).
// ---------------------------------------------------------------------------
__global__ __launch_bounds__(256)
void gat4_kernel(const float* __restrict__ features,
                 const int* __restrict__ node,
                 const int* __restrict__ neigh,
                 const float* __restrict__ w12g,   // [256]
                 const u16* __restrict__ MTb,      // [D][D] bf16, MTb[u][d]
                 float* __restrict__ out)          // [NB][D] fp32
{
    __shared__ u32   fbuf[128 * FSTR];     // 32 KB: 128 rows x 128 bf16
    __shared__ float zb[132];              // [n*33 + j] raw scores
    __shared__ float agg[512];             // [n*128 + d]

    const int t  = threadIdx.x;
    const int b4 = blockIdx.x * NPB;
    const int cc = t & 31;                 // float4 column in row (loop-invariant)
    const int r0 = t >> 5;                 // 0..7: starting row

    // score weight vectors, hoisted (w12g is tiny & L2-hot; coalesced float4)
    const float4* w4 = (const float4*)w12g;
    const float4 wlo = w4[cc];             // neighbour-row weights
    const float4 whi = w4[32 + cc];        // target-row weights

    // ---- P1a: batch all index loads (half-wave lanes share the address) ----
    int idx[16];
    #pragma unroll
    for (int i = 0; i < 16; ++i) {
        int r = r0 + 8 * i;                // 0..127: always a neighbour row
        idx[i] = neigh[(b4 + (r & 3)) * K + (r >> 2)];
    }

    // ---- P1b: batch all feature-row loads (16/17 independent chains) ----
    const float4* f4 = (const float4*)features;
    float4 v[16], vt;
    #pragma unroll
    for (int i = 0; i < 16; ++i)
        v[i] = f4[(size_t)idx[i] * 32 + cc];
    if (r0 < 4)                            // waves 0,1 only: the 4 target rows
        vt = f4[(size_t)node[b4 + r0] * 32 + cc];

    // ---- P1c: pack to LDS + fused score ----
    #pragma unroll
    for (int i = 0; i < 16; ++i) {
        int r = r0 + 8 * i;
        u32* dst = &fbuf[r * FSTR + cc * 2];
        dst[0] = packcvt(v[i].x, v[i].y);
        dst[1] = packcvt(v[i].z, v[i].w);
        float p = v[i].x * wlo.x + v[i].y * wlo.y + v[i].z * wlo.z + v[i].w * wlo.w;
        p += __shfl_xor(p, 1);
        p += __shfl_xor(p, 2);
        p += __shfl_xor(p, 4);
        p += __shfl_xor(p, 8);
        p += __shfl_xor(p, 16);
        if (cc == 0) zb[(r & 3) * 33 + (r >> 2)] = p;
    }
    if (r0 < 4) {                          // waves 0,1 only (wave-uniform branch)
        float p = vt.x * whi.x + vt.y * whi.y + vt.z * whi.z + vt.w * whi.w;
        p += __shfl_xor(p, 1);
        p += __shfl_xor(p, 2);
        p += __shfl_xor(p, 4);
        p += __shfl_xor(p, 8);
        p += __shfl_xor(p, 16);
        if (cc == 0) zb[r0 * 33 + 32] = p; // node r0's target score
    }
    __syncthreads();

    // ---- P2': per-wave softmax + aggregate (wave n owns node n) ----
    {
        const int n = t >> 6, l = t & 63, k32 = l & 31;
        float vsc = zb[n * 33 + k32] + zb[n * 33 + 32];
        vsc = vsc > 0.f ? vsc : 0.2f * vsc;                 // leaky relu
        float m = vsc;                                      // max over 32 (halves identical)
        m = fmaxf(m, __shfl_xor(m, 1));
        m = fmaxf(m, __shfl_xor(m, 2));
        m = fmaxf(m, __shfl_xor(m, 4));
        m = fmaxf(m, __shfl_xor(m, 8));
        m = fmaxf(m, __shfl_xor(m, 16));
        float e = __expf(vsc - m);
        float s = e;
        s += __shfl_xor(s, 1);
        s += __shfl_xor(s, 2);
        s += __shfl_xor(s, 4);
        s += __shfl_xor(s, 8);
        s += __shfl_xor(s, 16);
        const float a = e * (1.0f / s);                     // lane l holds alpha[k = l&31]

        float a0 = 0.f, a1 = 0.f;
        #pragma unroll
        for (int k = 0; k < K; ++k) {
            float al = __shfl(a, k);                        // readlane broadcast
            u32 vv = fbuf[(4 * k + n) * FSTR + l];
            a0 = fmaf(al, blo(vv), a0);
            a1 = fmaf(al, bhi(vv), a1);
        }
        agg[n * 128 + 2 * l]     = a0;
        agg[n * 128 + 2 * l + 1] = a1;
    }
    __syncthreads();

    // ---- P4: out[n][u] = sum_d agg[n][d] * MT[u][d]; thread t covers (nA,u),(nA+2,u)
    {
        int u  = t & 127;
        int nA = t >> 7;                      // 0 or 1
        const uint4* mrow = (const uint4*)(MTb + u * D);   // 16 x (8 bf16)
        const float* aggA = &agg[nA * 128];
        const float* aggB = &agg[(nA + 2) * 128];
        float accA0 = 0.f, accA1 = 0.f, accB0 = 0.f, accB1 = 0.f;
        #pragma unroll
        for (int q = 0; q < 16; ++q) {
            uint4 m4 = mrow[q];
            int d0 = q * 8;
            float m0 = blo(m4.x), m1 = bhi(m4.x), m2 = blo(m4.y), m3 = bhi(m4.y);
            float m4f = blo(m4.z), m5 = bhi(m4.z), m6 = blo(m4.w), m7 = bhi(m4.w);
            accA0 += aggA[d0] * m0 + aggA[d0+1] * m1 + aggA[d0+2] * m2 + aggA[d0+3] * m3;
            accA1 += aggA[d0+4] * m4f + aggA[d0+5] * m5 + aggA[d0+6] * m6 + aggA[d0+7] * m7;
            accB0 += aggB[d0] * m0 + aggB[d0+1] * m1 + aggB[d0+2] * m2 + aggB[d0+3] * m3;
            accB1 += aggB[d0+4] * m4f + aggB[d0+5] * m5 + aggB[d0+6] * m6 + aggB[d0+7] * m7;
        }
        out[(size_t)(b4 + nA) * D + u]     = accA0 + accA1;
        out[(size_t)(b4 + nA + 2) * D + u] = accB0 + accB1;
    }
}

// ---------------------------------------------------------------------------
// Fallback (ws too small): round-4 known-good fp32 path, scratch-free.
// ---------------------------------------------------------------------------
#define RS 33
#define RSF 132
__global__ __launch_bounds__(256)
void gat_fallback_kernel(const float* __restrict__ features, const int* __restrict__ node,
                         const int* __restrict__ neigh,
                         const float* __restrict__ k0, const float* __restrict__ k1,
                         const float* __restrict__ aw, const float* __restrict__ nw,
                         float* __restrict__ out)
{
    __shared__ float4 fbuf[NROWS * RS];
    __shared__ float w1[D], w2[D], h[D];
    __shared__ int   idxs[NROWS];
    __shared__ float psum[NROWS][8];
    __shared__ float zb[NROWS], alpha[K], agg[D];

    const int b = blockIdx.x, t = threadIdx.x;

    if (t < 128) {
        float a = 0.f;
        for (int e = 0; e < D; ++e) a = fmaf(k1[t * D + e], aw[e], a);
        w1[t] = a;
    } else {
        int d = t - 128;
        float a = 0.f;
        for (int e = 0; e < D; ++e) a = fmaf(k0[d * D + e], aw[128 + e], a);
        w2[d] = a;
    }
    if (t < K)       idxs[t] = neigh[b * K + t];
    else if (t == K) idxs[K] = node[b];
    __syncthreads();

    const float4* f4 = (const float4*)features;
    for (int c = t; c < NROWS * 32; c += 256) {
        int j = c >> 5, cc = c & 31;
        fbuf[j * RS + cc] = f4[(size_t)idxs[j] * 32 + cc];
    }
    __syncthreads();

    for (int task = t; task < NROWS * 8; task += 256) {
        int j = task >> 3, sub = task & 7;
        const float* w = (j < K) ? w1 : w2;
        const float4* r = &fbuf[j * RS + sub * 4];
        int d0 = sub * 16;
        float4 a0 = r[0], a1 = r[1], a2 = r[2], a3 = r[3];
        float acc;
        acc  = a0.x * w[d0 + 0]  + a0.y * w[d0 + 1]  + a0.z * w[d0 + 2]  + a0.w * w[d0 + 3];
        acc += a1.x * w[d0 + 4]  + a1.y * w[d0 + 5]  + a1.z * w[d0 + 6]  + a1.w * w[d0 + 7];
        acc += a2.x * w[d0 + 8]  + a2.y * w[d0 + 9]  + a2.z * w[d0 + 10] + a2.w * w[d0 + 11];
        acc += a3.x * w[d0 + 12] + a3.y * w[d0 + 13] + a3.z * w[d0 + 14] + a3.w * w[d0 + 15];
        psum[j][sub] = acc;
    }
    __syncthreads();

    if (t < NROWS) {
        float s = 0.f;
        #pragma unroll
        for (int i = 0; i < 8; ++i) s += psum[t][i];
        zb[t] = s;
    }
    __syncthreads();

    if (t == 0) {
        float c = zb[K];
        float m = -1e30f;
        #pragma unroll
        for (int k = 0; k < K; ++k) {
            float v = zb[k] + c;
            v = v > 0.f ? v : 0.2f * v;
            zb[k] = v;
            m = fmaxf(m, v);
        }
        float s = 0.f;
        #pragma unroll
        for (int k = 0; k < K; ++k) { float e = __expf(zb[k] - m); alpha[k] = e; s += e; }
        float inv = 1.f / s;
        #pragma unroll
        for (int k = 0; k < K; ++k) alpha[k] *= inv;
    }
    __syncthreads();

    const float* fb = (const float*)fbuf;
    if (t < D) {
        float a = 0.f;
        #pragma unroll
        for (int k = 0; k < K; ++k)
            a = fmaf(alpha[k], fb[k * RSF + t], a);
        agg[t] = a;
    }
    __syncthreads();

    if (t < 128) {
        float acc = 0.f;
        for (int d = 0; d < D; ++d) acc = fmaf(agg[d], k1[d * D + t], acc);
        h[t] = acc;
    }
    __syncthreads();
    if (t < 128) {
        float acc = 0.f;
        for (int e = 0; e < D; ++e) acc = fmaf(h[e], nw[e * D + t], acc);
        out[(size_t)b * D + t] = acc;
    }
}

extern "C" void kernel_launch(void* const* d_in, const int* in_sizes, int n_in,
                              void* d_out, int out_size, void* d_ws, size_t ws_size,
                              hipStream_t stream) {
    const float* features = (const float*)d_in[0];
    const int*   node     = (const int*)d_in[1];
    const int*   neigh    = (const int*)d_in[2];
    const float* k0       = (const float*)d_in[3];
    const float* k1       = (const float*)d_in[4];
    const float* aw       = (const float*)d_in[5];
    const float* nw       = (const float*)d_in[6];

    // ws layout: w12 (256 f32, 1 KB) | MTb (128*128 bf16, 32 KB)
    const size_t need = 256 * sizeof(float) + (size_t)D * D * sizeof(u16);
    if (ws_size >= need) {
        float* w12 = (float*)d_ws;
        u16*   MTb = (u16*)(w12 + 256);
        precompute_kernel<<<65, 256, 0, stream>>>(k0, k1, aw, nw, w12, MTb);
        gat4_kernel<<<NBLK, 256, 0, stream>>>(features, node, neigh, w12, MTb,
                                              (float*)d_out);
    } else {
        gat_fallback_kernel<<<NB, 256, 0, stream>>>(features, node, neigh,
                                                    k0, k1, aw, nw, (float*)d_out);
    }
}